// Round 2
// baseline (432.557 us; speedup 1.0000x reference)
//
#include <hip/hip_runtime.h>

// GAT on MI355X. Pipeline (6 dispatches + 1 memset):
//  M0 memset     : cnt = 0, ypart = 0 (single 64KB hipMemsetAsync)
//  K1 gemm_xh    : xh = x @ lin_w.T  [8192,256] f32 64x64 tiled; epilogue also
//                  writes bf16 copy xh_bf (halves agg gather traffic)
//  K2 att_deg    : a_src/a_dst per (node,head)  +  cnt[dst]++ histogram (merged)
//  K3 scan       : rowptr = exclusive prefix(cnt + 1/self-loop); wpos = copy
//  K4 scatter    : CSR bucket edges (+self loops) by dst + per-edge 8-head
//                  exp(leakyrelu) weights (computed once, not 256x)
//  K5 agg_dot    : FUSED agg + final dot. Per dst node block:
//                   (1) issue the 8 nt loads of out_w[c, i*256..] (known from
//                       blockIdx alone — independent of gather!)
//                   (2) gather: den = sum w, acc = sum w * xh_bf[src]
//                   (3) of = acc/den + bias; exchange row via LDS
//                   (4) 32 per-block dots vs the prefetched w, wave-reduce,
//                       atomicAdd into 256-bucket ypart.
//                  Gather latency hides under the 268 MB HBM stream; kills the
//                  out_flat 8MB write + 256MB L2 re-read of the old K6.
//  K6 finalize   : reduce ypart[256][32] + bias + softmax -> d_out[32]

namespace {
constexpr int  kN    = 8192;
constexpr int  kE    = 262144;
constexpr int  kTotE = kE + kN;          // 270336 (self loops appended)
constexpr long kK    = 2097152;          // N * H * C
constexpr int  kYB   = 256;              // ypart buckets
}

typedef float vfloat4 __attribute__((ext_vector_type(4)));  // native vec for nt loads

static __device__ __forceinline__ ushort f2bf(float f) {  // RNE f32->bf16
  unsigned u = __float_as_uint(f);
  return (ushort)((u + 0x7FFFu + ((u >> 16) & 1u)) >> 16);
}
static __device__ __forceinline__ float bf2f(ushort b) {
  return __uint_as_float(((unsigned)b) << 16);
}

// ---------------- K1: xh = x @ lin_w^T  (M=8192, N=256, K=256) ----------------
__global__ __launch_bounds__(256) void gemm_xh(const float* __restrict__ x,
                                               const float* __restrict__ lw,
                                               float* __restrict__ xh,
                                               ushort* __restrict__ xh_bf) {
  __shared__ float As[16][68];
  __shared__ float Bs[16][68];
  const int t  = threadIdx.x;
  const int tx = t & 15, ty = t >> 4;
  const int rowBase = blockIdx.x * 64;
  const int colBase = blockIdx.y * 64;
  const int lr = t >> 2;
  const int lk = (t & 3) * 4;

  float acc[4][4] = {};
  for (int kc = 0; kc < 256; kc += 16) {
    float4 av = *(const float4*)(x  + (long)(rowBase + lr) * 256 + kc + lk);
    float4 bv = *(const float4*)(lw + (long)(colBase + lr) * 256 + kc + lk);
    __syncthreads();
    As[lk + 0][lr] = av.x; As[lk + 1][lr] = av.y; As[lk + 2][lr] = av.z; As[lk + 3][lr] = av.w;
    Bs[lk + 0][lr] = bv.x; Bs[lk + 1][lr] = bv.y; Bs[lk + 2][lr] = bv.z; Bs[lk + 3][lr] = bv.w;
    __syncthreads();
#pragma unroll
    for (int k = 0; k < 16; k++) {
      float4 a4 = *(const float4*)(&As[k][ty * 4]);
      float4 b4 = *(const float4*)(&Bs[k][tx * 4]);
      float aa[4] = {a4.x, a4.y, a4.z, a4.w};
      float bb[4] = {b4.x, b4.y, b4.z, b4.w};
#pragma unroll
      for (int i = 0; i < 4; i++)
#pragma unroll
        for (int j = 0; j < 4; j++) acc[i][j] += aa[i] * bb[j];
    }
  }
#pragma unroll
  for (int i = 0; i < 4; i++) {
    const long row = rowBase + ty * 4 + i;
    float4 o = make_float4(acc[i][0], acc[i][1], acc[i][2], acc[i][3]);
    *(float4*)(xh + row * 256 + colBase + tx * 4) = o;
    ushort4 ob = make_ushort4(f2bf(o.x), f2bf(o.y), f2bf(o.z), f2bf(o.w));
    *(ushort4*)(xh_bf + row * 256 + colBase + tx * 4) = ob;
  }
}

// ------------- K2: per-(node,head) attention dots + degree histogram -------------
__global__ __launch_bounds__(256) void att_deg(const float* __restrict__ xh,
                                               const float* __restrict__ att_s,
                                               const float* __restrict__ att_d,
                                               const int* __restrict__ ei,
                                               float* __restrict__ a_src,
                                               float* __restrict__ a_dst,
                                               int* __restrict__ cnt) {
  const int n = blockIdx.x, t = threadIdx.x;  // t = h*32 + c
  float v = xh[(long)n * 256 + t];
  float s = v * att_s[t];
  float d = v * att_d[t];
#pragma unroll
  for (int off = 16; off; off >>= 1) {
    s += __shfl_down(s, off, 32);
    d += __shfl_down(d, off, 32);
  }
  if ((t & 31) == 0) {
    a_src[n * 8 + (t >> 5)] = s;
    a_dst[n * 8 + (t >> 5)] = d;
  }
  // merged degree histogram (cnt pre-zeroed by memsetAsync; self-loop added in scan)
  const int gid = n * 256 + t;
  if (gid < kE) atomicAdd(&cnt[ei[kE + gid]], 1);  // ei[1][e] = dst
}

// ---------------- K3: single-block exclusive scan (+1 self-loop each) ----------------
__global__ __launch_bounds__(1024) void scan_cnt(const int* __restrict__ cnt,
                                                 int* __restrict__ rowptr,
                                                 int* __restrict__ wpos) {
  __shared__ int s[1024];
  const int t = threadIdx.x;
  int v[8]; int sum = 0;
#pragma unroll
  for (int q = 0; q < 8; q++) { v[q] = cnt[t * 8 + q] + 1; sum += v[q]; }  // +1 self-loop
  s[t] = sum;
  __syncthreads();
  for (int off = 1; off < 1024; off <<= 1) {
    int add = (t >= off) ? s[t - off] : 0;
    __syncthreads();
    s[t] += add;
    __syncthreads();
  }
  int excl = s[t] - sum;
#pragma unroll
  for (int q = 0; q < 8; q++) {
    rowptr[t * 8 + q] = excl;
    wpos[t * 8 + q]   = excl;
    excl += v[q];
  }
  if (t == 1023) rowptr[kN] = s[1023];
}

// ---------------- K4: bucket edges by dst + per-edge 8-head weights ----------------
__global__ __launch_bounds__(256) void scatter_csr(const int* __restrict__ ei,
                                                   const float* __restrict__ a_src,
                                                   const float* __restrict__ a_dst,
                                                   int* __restrict__ wpos,
                                                   int* __restrict__ csr,
                                                   float* __restrict__ w8) {
  int idx = blockIdx.x * 256 + threadIdx.x;
  if (idx >= kTotE) return;
  int s, d;
  if (idx < kE) { s = ei[idx]; d = ei[kE + idx]; }
  else          { s = idx - kE; d = s; }
  int pos = atomicAdd(&wpos[d], 1);
  csr[pos] = s;
  float4 s0 = *(const float4*)(a_src + s * 8);
  float4 s1 = *(const float4*)(a_src + s * 8 + 4);
  float4 d0 = *(const float4*)(a_dst + d * 8);
  float4 d1 = *(const float4*)(a_dst + d * 8 + 4);
  float e[8] = {s0.x + d0.x, s0.y + d0.y, s0.z + d0.z, s0.w + d0.w,
                s1.x + d1.x, s1.y + d1.y, s1.z + d1.z, s1.w + d1.w};
  float w[8];
#pragma unroll
  for (int h = 0; h < 8; h++) {
    float ee = (e[h] > 0.f) ? e[h] : 0.2f * e[h];   // leaky_relu(0.2)
    w[h] = __expf(ee);                              // |e| <~ 5, no max-sub needed
  }
  float4* wp = (float4*)(w8 + (long)pos * 8);
  wp[0] = make_float4(w[0], w[1], w[2], w[3]);
  wp[1] = make_float4(w[4], w[5], w[6], w[7]);
}

// ---------- K5: fused weighted-gather aggregation + final dot ----------
// Block = dst node i. Phase 0 issues the 8 nt out_w loads (independent of the
// gather). Phase 1 gathers bf16 rows. Phase 2 exchanges the of-row via LDS and
// reduces the 32 channel dots, accumulating into 256-bucket ypart.
__global__ __launch_bounds__(256) void agg_dot(const ushort* __restrict__ xb,
                                               const float* __restrict__ w8,
                                               const int* __restrict__ rowptr,
                                               const int* __restrict__ csr,
                                               const float* __restrict__ bias,
                                               const float* __restrict__ w,
                                               float* __restrict__ ypart) {
  const int i = blockIdx.x, t = threadIdx.x, h = t >> 5;
  const int lane = t & 63, wid = t >> 6;

  // phase 0: prefetch this node's out_w slice — w[c][i*256 + lane*4], c = cc*4+wid
  const long wbase = (long)i * 256 + lane * 4;
  vfloat4 wv[8];
#pragma unroll
  for (int cc = 0; cc < 8; cc++) {
    const int c = cc * 4 + wid;
    wv[cc] = __builtin_nontemporal_load((const vfloat4*)(w + (long)c * kK + wbase));
  }

  // phase 1: gather aggregation (bf16 rows, unroll x8)
  const int beg = rowptr[i], end = rowptr[i + 1];
  float acc = 0.f, den = 0.f;
  int j = beg;
  for (; j + 8 <= end; j += 8) {
    int   s[8]; float ww[8]; float f[8];
#pragma unroll
    for (int q = 0; q < 8; q++) s[q] = csr[j + q];
#pragma unroll
    for (int q = 0; q < 8; q++) ww[q] = w8[(long)(j + q) * 8 + h];
#pragma unroll
    for (int q = 0; q < 8; q++) f[q] = bf2f(xb[(long)s[q] * 256 + t]);
#pragma unroll
    for (int q = 0; q < 8; q++) { den += ww[q]; acc += ww[q] * f[q]; }
  }
  for (; j < end; j++) {
    int s0 = csr[j];
    float w0 = w8[(long)j * 8 + h];
    den += w0;
    acc += w0 * bf2f(xb[(long)s0 * 256 + t]);
  }

  // phase 2: of-row through LDS, 32 per-block dots, wave reduce, bucket atomics
  __shared__ float ofs[256];
  __shared__ float yb[32];
  ofs[t] = acc / den + bias[t];
  __syncthreads();
  float4 f4 = *(const float4*)(ofs + lane * 4);
#pragma unroll
  for (int cc = 0; cc < 8; cc++) {
    float p = wv[cc].x * f4.x + wv[cc].y * f4.y + wv[cc].z * f4.z + wv[cc].w * f4.w;
    p += __shfl_down(p, 32, 64);
    p += __shfl_down(p, 16, 64);
    p += __shfl_down(p, 8, 64);
    p += __shfl_down(p, 4, 64);
    p += __shfl_down(p, 2, 64);
    p += __shfl_down(p, 1, 64);
    if (lane == 0) yb[cc * 4 + wid] = p;
  }
  __syncthreads();
  if (t < 32) atomicAdd(&ypart[(i & (kYB - 1)) * 32 + t], yb[t]);
}

// ---------------- K6: reduce ypart[256][32] + bias + softmax ----------------
__global__ __launch_bounds__(1024) void finalize(const float* __restrict__ ypart,
                                                 const float* __restrict__ ob,
                                                 float* __restrict__ out) {
  __shared__ float s[32][33];
  const int t = threadIdx.x;
  const int c = t & 31, r = t >> 5;
  float sum = 0.f;
  for (int q = r; q < kYB; q += 32) sum += ypart[q * 32 + c];  // 8 adds per thread
  s[c][r] = sum;
  __syncthreads();
  if (t < 32) {
    float y = ob[t];
#pragma unroll
    for (int r2 = 0; r2 < 32; r2++) y += s[t][r2];
    float m = y;
#pragma unroll
    for (int off = 16; off; off >>= 1) m = fmaxf(m, __shfl_xor(m, off, 32));
    float e = __expf(y - m);
    float d = e;
#pragma unroll
    for (int off = 16; off; off >>= 1) d += __shfl_xor(d, off, 32);
    out[t] = e / d;
  }
}

extern "C" void kernel_launch(void* const* d_in, const int* in_sizes, int n_in,
                              void* d_out, int out_size, void* d_ws, size_t ws_size,
                              hipStream_t stream) {
  (void)in_sizes; (void)n_in; (void)out_size; (void)ws_size;
  const float* x     = (const float*)d_in[0];
  const int*   ei    = (const int*)  d_in[1];
  const float* lin_w = (const float*)d_in[2];
  const float* att_s = (const float*)d_in[3];
  const float* att_d = (const float*)d_in[4];
  const float* bias  = (const float*)d_in[5];
  const float* out_w = (const float*)d_in[6];
  const float* out_b = (const float*)d_in[7];
  float* out = (float*)d_out;

  // workspace layout (~22.4 MB)
  float*  xh       = (float*)d_ws;
  float*  a_src    = xh + kK;
  float*  a_dst    = a_src + kN * 8;
  float*  w8       = a_dst + kN * 8;
  ushort* xh_bf    = (ushort*)(w8 + (long)kTotE * 8);
  int*    cnt      = (int*)(xh_bf + kK);
  float*  ypart    = (float*)(cnt + kN);          // kYB*32 floats, adjacent to cnt
  int*    rowptr   = (int*)(ypart + kYB * 32);
  int*    wpos     = rowptr + (kN + 1);
  int*    csr      = wpos + kN;

  // zero cnt + ypart in one memset (adjacent)
  (void)hipMemsetAsync(cnt, 0, kN * sizeof(int) + kYB * 32 * sizeof(float), stream);
  gemm_xh    <<<dim3(128, 4), 256, 0, stream>>>(x, lin_w, xh, xh_bf);
  att_deg    <<<kN, 256, 0, stream>>>(xh, att_s, att_d, ei, a_src, a_dst, cnt);
  scan_cnt   <<<1, 1024, 0, stream>>>(cnt, rowptr, wpos);
  scatter_csr<<<(kTotE + 255) / 256, 256, 0, stream>>>(ei, a_src, a_dst, wpos, csr, w8);
  agg_dot    <<<kN, 256, 0, stream>>>(xh_bf, w8, rowptr, csr, bias, out_w, ypart);
  finalize   <<<1, 1024, 0, stream>>>(ypart, out_b, out);
}

// Round 3
// 427.034 us; speedup vs baseline: 1.0129x; 1.0129x over previous
//
#include <hip/hip_runtime.h>

// GAT on MI355X. Pipeline (5 dispatches + 1 memset):
//  M0 memset       : cnt = 0, ypart = 0 (single hipMemsetAsync)
//  K1 gemm_att_hist: xh_bf = bf16(x @ lin_w.T)  [8192,256] 64x64 tiled.
//                    FUSED epilogue: each block's 64 cols = 2 whole heads ->
//                    a_src/a_dst dots reduced in-register (8-lane shuffles)
//                    from the f32 accumulators (bit-identical to the old
//                    store-xh-then-reload path). FUSED degree histogram
//                    (512 edges/block, issued up front, hides under GEMM).
//                    f32 xh buffer deleted (16 MB of traffic gone).
//  K2 scan         : rowptr = exclusive prefix(cnt + 1/self-loop); wpos copy.
//                    Wave-shuffle scan, 2 barriers (was 20-barrier Hillis-Steele).
//  K3 scatter      : CSR bucket edges (+self loops) by dst + per-edge 8-head
//                    exp(leakyrelu) weights
//  K4 agg_dot      : fused gather-aggregate + out_w dot (268 MB nt stream),
//                    bucketed atomics into ypart[256][32]
//  K5 finalize     : reduce ypart + bias + softmax -> d_out[32]

namespace {
constexpr int  kN    = 8192;
constexpr int  kE    = 262144;
constexpr int  kTotE = kE + kN;          // 270336 (self loops appended)
constexpr long kK    = 2097152;          // N * H * C
constexpr int  kYB   = 256;              // ypart buckets
}

typedef float vfloat4 __attribute__((ext_vector_type(4)));  // native vec for nt loads

static __device__ __forceinline__ ushort f2bf(float f) {  // RNE f32->bf16
  unsigned u = __float_as_uint(f);
  return (ushort)((u + 0x7FFFu + ((u >> 16) & 1u)) >> 16);
}
static __device__ __forceinline__ float bf2f(ushort b) {
  return __uint_as_float(((unsigned)b) << 16);
}

// ------- K1: xh_bf = bf16(x @ lin_w^T) + attention dots + degree histogram -------
// grid (128,4): rowBase = bx*64, colBase = by*64 (cols 64 = heads 2*by, 2*by+1)
__global__ __launch_bounds__(256) void gemm_att_hist(const float* __restrict__ x,
                                                     const float* __restrict__ lw,
                                                     const float* __restrict__ att_s,
                                                     const float* __restrict__ att_d,
                                                     const int* __restrict__ ei,
                                                     ushort* __restrict__ xh_bf,
                                                     float* __restrict__ a_src,
                                                     float* __restrict__ a_dst,
                                                     int* __restrict__ cnt) {
  __shared__ float As[16][68];
  __shared__ float Bs[16][68];
  const int t  = threadIdx.x;
  const int tx = t & 15, ty = t >> 4;
  const int rowBase = blockIdx.x * 64;
  const int colBase = blockIdx.y * 64;
  const int lr = t >> 2;
  const int lk = (t & 3) * 4;

  // degree histogram: 512 edges per block, fire-and-forget, hides under GEMM
  {
    const int bid = blockIdx.y * 128 + blockIdx.x;      // 0..511
    const int gid = bid * 512 + t;
    atomicAdd(&cnt[ei[kE + gid]], 1);                   // ei[1][e] = dst
    atomicAdd(&cnt[ei[kE + gid + 256]], 1);
  }

  float acc[4][4] = {};
  for (int kc = 0; kc < 256; kc += 16) {
    float4 av = *(const float4*)(x  + (long)(rowBase + lr) * 256 + kc + lk);
    float4 bv = *(const float4*)(lw + (long)(colBase + lr) * 256 + kc + lk);
    __syncthreads();
    As[lk + 0][lr] = av.x; As[lk + 1][lr] = av.y; As[lk + 2][lr] = av.z; As[lk + 3][lr] = av.w;
    Bs[lk + 0][lr] = bv.x; Bs[lk + 1][lr] = bv.y; Bs[lk + 2][lr] = bv.z; Bs[lk + 3][lr] = bv.w;
    __syncthreads();
#pragma unroll
    for (int k = 0; k < 16; k++) {
      float4 a4 = *(const float4*)(&As[k][ty * 4]);
      float4 b4 = *(const float4*)(&Bs[k][tx * 4]);
      float aa[4] = {a4.x, a4.y, a4.z, a4.w};
      float bb[4] = {b4.x, b4.y, b4.z, b4.w};
#pragma unroll
      for (int i = 0; i < 4; i++)
#pragma unroll
        for (int j = 0; j < 4; j++) acc[i][j] += aa[i] * bb[j];
    }
  }

  // epilogue A: bf16 store of this thread's 4x4 tile
#pragma unroll
  for (int i = 0; i < 4; i++) {
    const long row = rowBase + ty * 4 + i;
    ushort4 ob = make_ushort4(f2bf(acc[i][0]), f2bf(acc[i][1]),
                              f2bf(acc[i][2]), f2bf(acc[i][3]));
    *(ushort4*)(xh_bf + row * 256 + colBase + tx * 4) = ob;
  }

  // epilogue B: attention dots from the f32 accumulators.
  // cols tx*4..tx*4+3 of head (tx>>3); reduce over the 8 lanes with same ty,
  // tx in {0..7} (head 0) / {8..15} (head 1)  ->  8-lane shuffle groups.
  float4 as4 = *(const float4*)(att_s + colBase + tx * 4);
  float4 ad4 = *(const float4*)(att_d + colBase + tx * 4);
#pragma unroll
  for (int i = 0; i < 4; i++) {
    float s = acc[i][0] * as4.x + acc[i][1] * as4.y + acc[i][2] * as4.z + acc[i][3] * as4.w;
    float d = acc[i][0] * ad4.x + acc[i][1] * ad4.y + acc[i][2] * ad4.z + acc[i][3] * ad4.w;
#pragma unroll
    for (int off = 4; off; off >>= 1) {
      s += __shfl_down(s, off, 8);
      d += __shfl_down(d, off, 8);
    }
    if ((tx & 7) == 0) {
      const int row  = rowBase + ty * 4 + i;
      const int head = blockIdx.y * 2 + (tx >> 3);
      a_src[row * 8 + head] = s;
      a_dst[row * 8 + head] = d;
    }
  }
}

// ---------------- K2: single-block exclusive scan (+1 self-loop each) ----------------
// wave-shuffle scan: 16 waves x 64 lanes x 8 elems, 2 barriers total
__global__ __launch_bounds__(1024) void scan_cnt(const int* __restrict__ cnt,
                                                 int* __restrict__ rowptr,
                                                 int* __restrict__ wpos) {
  __shared__ int wsum[16];
  const int t = threadIdx.x, lane = t & 63, w = t >> 6;
  int v[8]; int sum = 0;
#pragma unroll
  for (int q = 0; q < 8; q++) { v[q] = cnt[t * 8 + q] + 1; sum += v[q]; }  // +1 self-loop
  int sc = sum;                                  // inclusive wave scan
#pragma unroll
  for (int off = 1; off < 64; off <<= 1) {
    int n = __shfl_up(sc, off, 64);
    if (lane >= off) sc += n;
  }
  if (lane == 63) wsum[w] = sc;
  __syncthreads();
  if (t < 16) {                                   // scan the 16 wave totals
    int ws = wsum[t];
#pragma unroll
    for (int off = 1; off < 16; off <<= 1) {
      int n = __shfl_up(ws, off, 16);
      if ((t & 15) >= off) ws += n;
    }
    wsum[t] = ws;
  }
  __syncthreads();
  int excl = (w ? wsum[w - 1] : 0) + sc - sum;
#pragma unroll
  for (int q = 0; q < 8; q++) {
    rowptr[t * 8 + q] = excl;
    wpos[t * 8 + q]   = excl;
    excl += v[q];
  }
  if (t == 1023) rowptr[kN] = excl;               // grand total
}

// ---------------- K3: bucket edges by dst + per-edge 8-head weights ----------------
__global__ __launch_bounds__(256) void scatter_csr(const int* __restrict__ ei,
                                                   const float* __restrict__ a_src,
                                                   const float* __restrict__ a_dst,
                                                   int* __restrict__ wpos,
                                                   int* __restrict__ csr,
                                                   float* __restrict__ w8) {
  int idx = blockIdx.x * 256 + threadIdx.x;
  if (idx >= kTotE) return;
  int s, d;
  if (idx < kE) { s = ei[idx]; d = ei[kE + idx]; }
  else          { s = idx - kE; d = s; }
  int pos = atomicAdd(&wpos[d], 1);
  csr[pos] = s;
  float4 s0 = *(const float4*)(a_src + s * 8);
  float4 s1 = *(const float4*)(a_src + s * 8 + 4);
  float4 d0 = *(const float4*)(a_dst + d * 8);
  float4 d1 = *(const float4*)(a_dst + d * 8 + 4);
  float e[8] = {s0.x + d0.x, s0.y + d0.y, s0.z + d0.z, s0.w + d0.w,
                s1.x + d1.x, s1.y + d1.y, s1.z + d1.z, s1.w + d1.w};
  float w[8];
#pragma unroll
  for (int h = 0; h < 8; h++) {
    float ee = (e[h] > 0.f) ? e[h] : 0.2f * e[h];   // leaky_relu(0.2)
    w[h] = __expf(ee);                              // |e| <~ 5, no max-sub needed
  }
  float4* wp = (float4*)(w8 + (long)pos * 8);
  wp[0] = make_float4(w[0], w[1], w[2], w[3]);
  wp[1] = make_float4(w[4], w[5], w[6], w[7]);
}

// ---------- K4: fused weighted-gather aggregation + final dot ----------
// Block = dst node i. Phase 0 issues the 8 nt out_w loads (independent of the
// gather). Phase 1 gathers bf16 rows. Phase 2 exchanges the of-row via LDS and
// reduces the 32 channel dots, accumulating into 256-bucket ypart.
__global__ __launch_bounds__(256) void agg_dot(const ushort* __restrict__ xb,
                                               const float* __restrict__ w8,
                                               const int* __restrict__ rowptr,
                                               const int* __restrict__ csr,
                                               const float* __restrict__ bias,
                                               const float* __restrict__ w,
                                               float* __restrict__ ypart) {
  const int i = blockIdx.x, t = threadIdx.x, h = t >> 5;
  const int lane = t & 63, wid = t >> 6;

  // phase 0: prefetch this node's out_w slice — w[c][i*256 + lane*4], c = cc*4+wid
  const long wbase = (long)i * 256 + lane * 4;
  vfloat4 wv[8];
#pragma unroll
  for (int cc = 0; cc < 8; cc++) {
    const int c = cc * 4 + wid;
    wv[cc] = __builtin_nontemporal_load((const vfloat4*)(w + (long)c * kK + wbase));
  }

  // phase 1: gather aggregation (bf16 rows, unroll x8)
  const int beg = rowptr[i], end = rowptr[i + 1];
  float acc = 0.f, den = 0.f;
  int j = beg;
  for (; j + 8 <= end; j += 8) {
    int   s[8]; float ww[8]; float f[8];
#pragma unroll
    for (int q = 0; q < 8; q++) s[q] = csr[j + q];
#pragma unroll
    for (int q = 0; q < 8; q++) ww[q] = w8[(long)(j + q) * 8 + h];
#pragma unroll
    for (int q = 0; q < 8; q++) f[q] = bf2f(xb[(long)s[q] * 256 + t]);
#pragma unroll
    for (int q = 0; q < 8; q++) { den += ww[q]; acc += ww[q] * f[q]; }
  }
  for (; j < end; j++) {
    int s0 = csr[j];
    float w0 = w8[(long)j * 8 + h];
    den += w0;
    acc += w0 * bf2f(xb[(long)s0 * 256 + t]);
  }

  // phase 2: of-row through LDS, 32 per-block dots, wave reduce, bucket atomics
  __shared__ float ofs[256];
  __shared__ float yb[32];
  ofs[t] = acc / den + bias[t];
  __syncthreads();
  float4 f4 = *(const float4*)(ofs + lane * 4);
#pragma unroll
  for (int cc = 0; cc < 8; cc++) {
    float p = wv[cc].x * f4.x + wv[cc].y * f4.y + wv[cc].z * f4.z + wv[cc].w * f4.w;
    p += __shfl_down(p, 32, 64);
    p += __shfl_down(p, 16, 64);
    p += __shfl_down(p, 8, 64);
    p += __shfl_down(p, 4, 64);
    p += __shfl_down(p, 2, 64);
    p += __shfl_down(p, 1, 64);
    if (lane == 0) yb[cc * 4 + wid] = p;
  }
  __syncthreads();
  if (t < 32) atomicAdd(&ypart[(i & (kYB - 1)) * 32 + t], yb[t]);
}

// ---------------- K5: reduce ypart[256][32] + bias + softmax ----------------
__global__ __launch_bounds__(1024) void finalize(const float* __restrict__ ypart,
                                                 const float* __restrict__ ob,
                                                 float* __restrict__ out) {
  __shared__ float s[32][33];
  const int t = threadIdx.x;
  const int c = t & 31, r = t >> 5;
  float sum = 0.f;
  for (int q = r; q < kYB; q += 32) sum += ypart[q * 32 + c];  // 8 adds per thread
  s[c][r] = sum;
  __syncthreads();
  if (t < 32) {
    float y = ob[t];
#pragma unroll
    for (int r2 = 0; r2 < 32; r2++) y += s[t][r2];
    float m = y;
#pragma unroll
    for (int off = 16; off; off >>= 1) m = fmaxf(m, __shfl_xor(m, off, 32));
    float e = __expf(y - m);
    float d = e;
#pragma unroll
    for (int off = 16; off; off >>= 1) d += __shfl_xor(d, off, 32);
    out[t] = e / d;
  }
}

extern "C" void kernel_launch(void* const* d_in, const int* in_sizes, int n_in,
                              void* d_out, int out_size, void* d_ws, size_t ws_size,
                              hipStream_t stream) {
  (void)in_sizes; (void)n_in; (void)out_size; (void)ws_size;
  const float* x     = (const float*)d_in[0];
  const int*   ei    = (const int*)  d_in[1];
  const float* lin_w = (const float*)d_in[2];
  const float* att_s = (const float*)d_in[3];
  const float* att_d = (const float*)d_in[4];
  const float* bias  = (const float*)d_in[5];
  const float* out_w = (const float*)d_in[6];
  const float* out_b = (const float*)d_in[7];
  float* out = (float*)d_out;

  // workspace layout (~14 MB)
  float*  a_src    = (float*)d_ws;
  float*  a_dst    = a_src + kN * 8;
  float*  w8       = a_dst + kN * 8;
  ushort* xh_bf    = (ushort*)(w8 + (long)kTotE * 8);
  int*    cnt      = (int*)(xh_bf + kK);
  float*  ypart    = (float*)(cnt + kN);          // kYB*32 floats, adjacent to cnt
  int*    rowptr   = (int*)(ypart + kYB * 32);
  int*    wpos     = rowptr + (kN + 1);
  int*    csr      = wpos + kN;

  // zero cnt + ypart in one memset (adjacent)
  (void)hipMemsetAsync(cnt, 0, kN * sizeof(int) + kYB * 32 * sizeof(float), stream);
  gemm_att_hist<<<dim3(128, 4), 256, 0, stream>>>(x, lin_w, att_s, att_d, ei,
                                                  xh_bf, a_src, a_dst, cnt);
  scan_cnt   <<<1, 1024, 0, stream>>>(cnt, rowptr, wpos);
  scatter_csr<<<(kTotE + 255) / 256, 256, 0, stream>>>(ei, a_src, a_dst, wpos, csr, w8);
  agg_dot    <<<kN, 256, 0, stream>>>(xh_bf, w8, rowptr, csr, bias, out_w, ypart);
  finalize   <<<1, 1024, 0, stream>>>(ypart, out_b, out);
}